// Round 7
// baseline (105.253 us; speedup 1.0000x reference)
//
#include <hip/hip_runtime.h>
#include <hip/hip_bf16.h>

// Problem constants
#define NB    4096          // batch
#define ND    256           // dim
#define NP    2             // positives per anchor
#define TOT   (NB * 3)      // 12288 rows: [a | p0 | p1]
#define NCHUNK 48           // 3 parts x 16 chunks; each chunk within one part
#define COLS_PER_CHUNK (TOT / NCHUNK)          // 256
#define TILES (COLS_PER_CHUNK / 16)            // 16
#define PITCH 528                               // 512B row + 16B pad (conflict-free)
#define NEG_INIT (-4.0f)

typedef __bf16 bf16x8 __attribute__((ext_vector_type(8)));
typedef float  f32x4  __attribute__((ext_vector_type(4)));

// ws layout (bytes)
#define WS_F_OFF    0                            // ushort[12288*256] bf16 normalized
#define WS_POS_OFF  (TOT * ND * 2)               // float[4096*2] pos distances
#define WS_PART_OFF (WS_POS_OFF + NB * NP * 4)   // float[3][4096][16] partial maxima

__device__ __forceinline__ unsigned short f2bf(float f) {
    unsigned u = __float_as_uint(f);
    u += 0x7fffu + ((u >> 16) & 1u);   // round-to-nearest-even
    return (unsigned short)(u >> 16);
}

// Kernel 1: normalize rows of [a | p0 | p1] -> bf16 matrix F; p-rows also emit
// the exact fp32 positive distance. One wave per row.
__global__ void norm_pos_kernel(const float* __restrict__ anchor,
                                const float* __restrict__ positive,
                                unsigned short* __restrict__ F,
                                float* __restrict__ posArr) {
    int wid = threadIdx.x >> 6, lane = threadIdx.x & 63;
    int row = blockIdx.x * 4 + wid;              // grid = 3072
    if (row < NB) {
        const float* src = anchor + (size_t)row * ND;
        float4 x = *(const float4*)(src + lane * 4);
        float ss = x.x * x.x + x.y * x.y + x.z * x.z + x.w * x.w;
        #pragma unroll
        for (int m = 1; m < 64; m <<= 1) ss += __shfl_xor(ss, m, 64);
        float inv = 1.0f / fmaxf(sqrtf(ss), 1e-12f);
        ushort4 o;
        o.x = f2bf(x.x * inv); o.y = f2bf(x.y * inv);
        o.z = f2bf(x.z * inv); o.w = f2bf(x.w * inv);
        *(ushort4*)(F + (size_t)row * ND + lane * 4) = o;
    } else {
        int q = row - NB;
        int v = q >> 12;                         // 0 or 1
        int j = q & (NB - 1);
        const float* sp = positive + (size_t)(j * NP + v) * ND;
        const float* sa = anchor + (size_t)j * ND;
        float4 xp = *(const float4*)(sp + lane * 4);
        float4 xa = *(const float4*)(sa + lane * 4);
        float sspv = xp.x * xp.x + xp.y * xp.y + xp.z * xp.z + xp.w * xp.w;
        float ssa  = xa.x * xa.x + xa.y * xa.y + xa.z * xa.z + xa.w * xa.w;
        float dot  = xa.x * xp.x + xa.y * xp.y + xa.z * xp.z + xa.w * xp.w;
        #pragma unroll
        for (int m = 1; m < 64; m <<= 1) {
            sspv += __shfl_xor(sspv, m, 64);
            ssa  += __shfl_xor(ssa, m, 64);
            dot  += __shfl_xor(dot, m, 64);
        }
        float invp = 1.0f / fmaxf(sqrtf(sspv), 1e-12f);
        ushort4 o;
        o.x = f2bf(xp.x * invp); o.y = f2bf(xp.y * invp);
        o.z = f2bf(xp.z * invp); o.w = f2bf(xp.w * invp);
        *(ushort4*)(F + (size_t)row * ND + lane * 4) = o;
        if (lane == 0) {
            float inva = 1.0f / fmaxf(sqrtf(ssa), 1e-12f);
            float dn = dot * inva * invp;
            float sq = 2.0f - 2.0f * dn;
            posArr[j * NP + v] = sqrtf(fmaxf(sq, 1e-12f));
        }
    }
}

// Kernel 2: fused masked-max Gram. Block = 4 waves x 64 rows = 256 rows;
// LDS-staged double-buffered 16-col B tiles shared by all 4 waves.
//
// Swizzle hypothesis v2 (CONTIGUOUS block->XCD ranges, ids 96x..96x+95 on
// XCD x): chunk = id>>4, rbi = id&15. Any contiguous 96-id window then
// touches 6 B-chunks (0.79 MB) x 16 A row-blocks (2.1 MB) = 2.9 MB < 4 MB
// per-XCD L2, so the 196 MB of logical A/B reads become L2 hits.
// (Round-robin id%8 hypothesis tested R5/R6: neutral -> rejected.)
__global__ __launch_bounds__(256) void gram_max_kernel(
        const unsigned short* __restrict__ F,
        const int* __restrict__ labels,
        float* __restrict__ partials) {
    __shared__ unsigned char lds[2][16 * PITCH];
    __shared__ int slab[COLS_PER_CHUNK];         // column labels for this chunk
    int tid = threadIdx.x;
    int wid = tid >> 6, lane = tid & 63;
    int l15 = lane & 15, quad = lane >> 4;

    int id = blockIdx.x;                         // 0..767
    int chunk = id >> 4;                         // 0..47 (16 consecutive ids share)
    int rbi   = id & 15;                         // 0..15 row-block index

    int rowBase = rbi * 256 + wid * 64;
    int col0 = chunk * COLS_PER_CHUNK;
    int part = col0 >> 12;                       // block-uniform: 0=aa, 1=p0, 2=p1
    const unsigned char* Fb = (const unsigned char*)F;

    // Stage this chunk's 256 column labels into LDS (labels repeat mod NB).
    slab[tid] = labels[(col0 & (NB - 1)) + tid];

    // Staging map (conflict-free): 16 threads per column, each thread two 16B
    // segments at sseg*16 and sseg*16+256.
    int scol = tid >> 4, sseg = tid & 15;

    // Preload A fragments: af[s][kk] covers rows rowBase+s*16.., K = kk*32.
    bf16x8 af[4][8];
    #pragma unroll
    for (int s = 0; s < 4; ++s) {
        const unsigned char* ar = Fb + (size_t)(rowBase + s * 16 + l15) * 512 + quad * 16;
        #pragma unroll
        for (int kk = 0; kk < 8; ++kk)
            af[s][kk] = *(const bf16x8*)(ar + kk * 64);
    }
    // Row labels, byte-packed (labels < 200 fit a byte): rlp[s] holds the 4
    // C rows (quad*4+r) of set s.
    unsigned rlp[4];
    #pragma unroll
    for (int s = 0; s < 4; ++s) {
        const int* lb = labels + rowBase + s * 16 + quad * 4;
        rlp[s] = (unsigned)lb[0] | ((unsigned)lb[1] << 8)
               | ((unsigned)lb[2] << 16) | ((unsigned)lb[3] << 24);
    }

    float vmax[4][4];
    #pragma unroll
    for (int s = 0; s < 4; ++s)
        #pragma unroll
        for (int r = 0; r < 4; ++r) vmax[s][r] = NEG_INIT;

    float4 r0, r1;  // prefetch registers (one 16-col tile / block)
    auto gload = [&](int ct) {
        const unsigned char* g = Fb + (size_t)(col0 + ct * 16 + scol) * 512 + sseg * 16;
        r0 = *(const float4*)g;
        r1 = *(const float4*)(g + 256);
    };
    auto swrite = [&](int buf) {
        unsigned char* p = &lds[buf][scol * PITCH + sseg * 16];
        *(float4*)p = r0;
        *(float4*)(p + 256) = r1;
    };

    gload(0); swrite(0);
    gload(1);
    __syncthreads();

    for (int ct = 0; ct < TILES; ++ct) {
        int buf = ct & 1;
        bf16x8 bfr[8];
        #pragma unroll
        for (int kk = 0; kk < 8; ++kk)
            bfr[kk] = *(const bf16x8*)&lds[buf][l15 * PITCH + quad * 16 + kk * 64];

        if (ct + 1 < TILES) swrite(buf ^ 1);   // stage next tile (regs already loaded)
        if (ct + 2 < TILES) gload(ct + 2);     // prefetch tile after next

        int lc = slab[ct * 16 + l15];          // column label
        unsigned lcq = (unsigned)lc * 0x01010101u;

        // 4 independent MFMA chains (one per 16-row set), depth 8
        f32x4 acc[4];
        #pragma unroll
        for (int s = 0; s < 4; ++s) acc[s] = (f32x4){0.f, 0.f, 0.f, 0.f};
        #pragma unroll
        for (int kk = 0; kk < 8; ++kk)
            #pragma unroll
            for (int s = 0; s < 4; ++s)
                acc[s] = __builtin_amdgcn_mfma_f32_16x16x32_bf16(af[s][kk], bfr[kk], acc[s], 0, 0, 0);

        #pragma unroll
        for (int s = 0; s < 4; ++s) {
            unsigned x = rlp[s] ^ lcq;         // byte r == 0 iff labels equal
            #pragma unroll
            for (int r = 0; r < 4; ++r) {
                bool neq = ((x >> (8 * r)) & 0xffu) != 0u;
                vmax[s][r] = fmaxf(vmax[s][r], neq ? acc[s][r] : NEG_INIT);
            }
        }
        __syncthreads();
    }

    // Reduce max across the 16 column-lanes (same quad = same rows)
    #pragma unroll
    for (int m = 1; m < 16; m <<= 1)
        #pragma unroll
        for (int s = 0; s < 4; ++s)
            #pragma unroll
            for (int r = 0; r < 4; ++r)
                vmax[s][r] = fmaxf(vmax[s][r], __shfl_xor(vmax[s][r], m, 64));

    if (l15 == 0) {
        #pragma unroll
        for (int s = 0; s < 4; ++s)
            #pragma unroll
            for (int r = 0; r < 4; ++r) {
                int row = rowBase + s * 16 + quad * 4 + r;
                partials[(size_t)part * NB * 16 + (size_t)row * 16 + (chunk & 15)] = vmax[s][r];
            }
    }
}

// Kernel 3: combine per-part chunk partials -> neg distances -> hinge -> mean.
__global__ void finalize_kernel(const float* __restrict__ partials,
                                const float* __restrict__ posArr,
                                float* __restrict__ out) {
    int row = blockIdx.x * 256 + threadIdx.x;    // grid = 16 -> 4096 rows
    const float* pa = partials + (size_t)row * 16;
    const float* pb = pa + (size_t)NB * 16;
    const float* pc = pb + (size_t)NB * 16;
    float ma = NEG_INIT, m0 = NEG_INIT, m1 = NEG_INIT;
    #pragma unroll
    for (int j = 0; j < 16; ++j) {
        ma = fmaxf(ma, pa[j]);
        m0 = fmaxf(m0, pb[j]);
        m1 = fmaxf(m1, pc[j]);
    }
    float n0 = sqrtf(fmaxf(2.0f - 2.0f * fmaxf(ma, m0), 1e-12f));
    float n1 = sqrtf(fmaxf(2.0f - 2.0f * fmaxf(ma, m1), 1e-12f));
    float l = fmaxf(posArr[row * 2 + 0] - n0 + 1.0f, 0.0f)
            + fmaxf(posArr[row * 2 + 1] - n1 + 1.0f, 0.0f);
    int lane = threadIdx.x & 63, wid = threadIdx.x >> 6;
    #pragma unroll
    for (int m = 1; m < 64; m <<= 1) l += __shfl_xor(l, m, 64);
    __shared__ float wsum[4];
    if (lane == 0) wsum[wid] = l;
    __syncthreads();
    if (threadIdx.x == 0) {
        float s = wsum[0] + wsum[1] + wsum[2] + wsum[3];
        atomicAdd(out, s * (1.0f / (NB * NP)));
    }
}

extern "C" void kernel_launch(void* const* d_in, const int* in_sizes, int n_in,
                              void* d_out, int out_size, void* d_ws, size_t ws_size,
                              hipStream_t stream) {
    const float* anchor   = (const float*)d_in[0];
    const float* positive = (const float*)d_in[1];
    const int*   labels   = (const int*)d_in[2];
    float* out = (float*)d_out;

    unsigned short* F = (unsigned short*)((char*)d_ws + WS_F_OFF);
    float* posArr     = (float*)((char*)d_ws + WS_POS_OFF);
    float* partials   = (float*)((char*)d_ws + WS_PART_OFF);

    norm_pos_kernel<<<TOT / 4, 256, 0, stream>>>(anchor, positive, F, posArr);
    gram_max_kernel<<<(NB / 256) * NCHUNK, 256, 0, stream>>>(F, labels, partials);
    hipMemsetAsync(d_out, 0, sizeof(float), stream);
    finalize_kernel<<<NB / 256, 256, 0, stream>>>(partials, posArr, out);
}

// Round 8
// 100.511 us; speedup vs baseline: 1.0472x; 1.0472x over previous
//
#include <hip/hip_runtime.h>
#include <hip/hip_bf16.h>

// Problem constants
#define NB    4096          // batch
#define ND    256           // dim
#define NP    2             // positives per anchor
#define TOT   (NB * 3)      // 12288 rows: [a | p0 | p1]
#define RB    256           // row bytes in F (fp8: 1 B/elem)
#define NCHUNK 48           // 3 parts x 16 chunks; each chunk within one part
#define COLS_PER_CHUNK (TOT / NCHUNK)          // 256
#define TILES (COLS_PER_CHUNK / 16)            // 16
#define PITCH 264                               // 256B col + 8B pad: balanced banks
#define NEG_INIT (-4.0f)

typedef float f32x4 __attribute__((ext_vector_type(4)));

// ws layout (bytes)
#define WS_F_OFF    0                            // uchar[12288*256] fp8 normalized
#define WS_POS_OFF  (TOT * RB)                   // float[4096*2] pos distances
#define WS_PART_OFF (WS_POS_OFF + NB * NP * 4)   // float[3][4096][16] partial maxima

// Kernel 1: normalize rows of [a | p0 | p1] -> fp8 e4m3 matrix F; p-rows also
// emit the exact fp32 positive distance. One wave per row; lane packs 4 elems
// into one int via v_cvt_pk_fp8_f32 (OCP e4m3fn on gfx950).
__global__ void norm_pos_kernel(const float* __restrict__ anchor,
                                const float* __restrict__ positive,
                                unsigned char* __restrict__ F,
                                float* __restrict__ posArr) {
    int wid = threadIdx.x >> 6, lane = threadIdx.x & 63;
    int row = blockIdx.x * 4 + wid;              // grid = 3072
    if (row < NB) {
        const float* src = anchor + (size_t)row * ND;
        float4 x = *(const float4*)(src + lane * 4);
        float ss = x.x * x.x + x.y * x.y + x.z * x.z + x.w * x.w;
        #pragma unroll
        for (int m = 1; m < 64; m <<= 1) ss += __shfl_xor(ss, m, 64);
        float inv = 1.0f / fmaxf(sqrtf(ss), 1e-12f);
        int pk = __builtin_amdgcn_cvt_pk_fp8_f32(x.x * inv, x.y * inv, 0, false);
        pk = __builtin_amdgcn_cvt_pk_fp8_f32(x.z * inv, x.w * inv, pk, true);
        *(int*)(F + (size_t)row * RB + lane * 4) = pk;
    } else {
        int q = row - NB;
        int v = q >> 12;                         // 0 or 1
        int j = q & (NB - 1);
        const float* sp = positive + (size_t)(j * NP + v) * ND;
        const float* sa = anchor + (size_t)j * ND;
        float4 xp = *(const float4*)(sp + lane * 4);
        float4 xa = *(const float4*)(sa + lane * 4);
        float sspv = xp.x * xp.x + xp.y * xp.y + xp.z * xp.z + xp.w * xp.w;
        float ssa  = xa.x * xa.x + xa.y * xa.y + xa.z * xa.z + xa.w * xa.w;
        float dot  = xa.x * xp.x + xa.y * xp.y + xa.z * xp.z + xa.w * xp.w;
        #pragma unroll
        for (int m = 1; m < 64; m <<= 1) {
            sspv += __shfl_xor(sspv, m, 64);
            ssa  += __shfl_xor(ssa, m, 64);
            dot  += __shfl_xor(dot, m, 64);
        }
        float invp = 1.0f / fmaxf(sqrtf(sspv), 1e-12f);
        int pk = __builtin_amdgcn_cvt_pk_fp8_f32(xp.x * invp, xp.y * invp, 0, false);
        pk = __builtin_amdgcn_cvt_pk_fp8_f32(xp.z * invp, xp.w * invp, pk, true);
        *(int*)(F + (size_t)row * RB + lane * 4) = pk;
        if (lane == 0) {
            float inva = 1.0f / fmaxf(sqrtf(ssa), 1e-12f);
            float dn = dot * inva * invp;
            float sq = 2.0f - 2.0f * dn;
            posArr[j * NP + v] = sqrtf(fmaxf(sq, 1e-12f));
        }
    }
}

// Kernel 2: fused masked-max Gram in FP8. Block = 4 waves x 64 rows = 256
// rows; LDS-staged double-buffered 16-col B tiles shared by all 4 waves.
// fp8 16x16x32 MFMA runs at the bf16 rate, so halving bytes halves the
// memory side without touching the FLOP floor.
__global__ __launch_bounds__(256) void gram_max_kernel(
        const unsigned char* __restrict__ F,
        const int* __restrict__ labels,
        float* __restrict__ partials) {
    __shared__ unsigned char lds[2][16 * PITCH];
    __shared__ int slab[COLS_PER_CHUNK];         // column labels for this chunk
    int tid = threadIdx.x;
    int wid = tid >> 6, lane = tid & 63;
    int l15 = lane & 15, quad = lane >> 4;

    int id = blockIdx.x;                         // 0..767
    int chunk = id >> 4;                         // 0..47
    int rbi   = id & 15;                         // 0..15 row-block index

    int rowBase = rbi * 256 + wid * 64;
    int col0 = chunk * COLS_PER_CHUNK;
    int part = col0 >> 12;                       // block-uniform: 0=aa, 1=p0, 2=p1
    const unsigned char* Fb = F;

    // Stage this chunk's 256 column labels into LDS (labels repeat mod NB).
    slab[tid] = labels[(col0 & (NB - 1)) + tid];

    // Staging map: 16 threads per column, one 16B segment each (col = 256 B).
    int scol = tid >> 4, sseg = tid & 15;

    // Preload A fragments: af[s][kk] = 8 consecutive fp8 K-bytes for row
    // rowBase+s*16+l15 at K-offset quad*8 + kk*32. (Same lane mapping as the
    // verified bf16 16x16x32 layout: 8 elems/lane, quad selects K-group.)
    long af[4][8];
    #pragma unroll
    for (int s = 0; s < 4; ++s) {
        const unsigned char* ar = Fb + (size_t)(rowBase + s * 16 + l15) * RB + quad * 8;
        #pragma unroll
        for (int kk = 0; kk < 8; ++kk)
            af[s][kk] = *(const long*)(ar + kk * 32);
    }
    // Row labels, byte-packed (labels < 200 fit a byte).
    unsigned rlp[4];
    #pragma unroll
    for (int s = 0; s < 4; ++s) {
        const int* lb = labels + rowBase + s * 16 + quad * 4;
        rlp[s] = (unsigned)lb[0] | ((unsigned)lb[1] << 8)
               | ((unsigned)lb[2] << 16) | ((unsigned)lb[3] << 24);
    }

    float vmax[4][4];
    #pragma unroll
    for (int s = 0; s < 4; ++s)
        #pragma unroll
        for (int r = 0; r < 4; ++r) vmax[s][r] = NEG_INIT;

    float4 r0;  // prefetch register (16 B per thread per tile)
    auto gload = [&](int ct) {
        const unsigned char* g = Fb + (size_t)(col0 + ct * 16 + scol) * RB + sseg * 16;
        r0 = *(const float4*)g;
    };
    auto swrite = [&](int buf) {
        *(float4*)&lds[buf][scol * PITCH + sseg * 16] = r0;
    };

    gload(0); swrite(0);
    gload(1);
    __syncthreads();

    for (int ct = 0; ct < TILES; ++ct) {
        int buf = ct & 1;
        long bfr[8];
        #pragma unroll
        for (int kk = 0; kk < 8; ++kk)
            bfr[kk] = *(const long*)&lds[buf][l15 * PITCH + quad * 8 + kk * 32];

        if (ct + 1 < TILES) swrite(buf ^ 1);   // stage next tile (regs already loaded)
        if (ct + 2 < TILES) gload(ct + 2);     // prefetch tile after next

        int lc = slab[ct * 16 + l15];          // column label
        unsigned lcq = (unsigned)lc * 0x01010101u;

        // 4 independent MFMA chains (one per 16-row set), depth 8
        f32x4 acc[4];
        #pragma unroll
        for (int s = 0; s < 4; ++s) acc[s] = (f32x4){0.f, 0.f, 0.f, 0.f};
        #pragma unroll
        for (int kk = 0; kk < 8; ++kk)
            #pragma unroll
            for (int s = 0; s < 4; ++s)
                acc[s] = __builtin_amdgcn_mfma_f32_16x16x32_fp8_fp8(af[s][kk], bfr[kk], acc[s], 0, 0, 0);

        #pragma unroll
        for (int s = 0; s < 4; ++s) {
            unsigned x = rlp[s] ^ lcq;         // byte r == 0 iff labels equal
            #pragma unroll
            for (int r = 0; r < 4; ++r) {
                bool neq = ((x >> (8 * r)) & 0xffu) != 0u;
                vmax[s][r] = fmaxf(vmax[s][r], neq ? acc[s][r] : NEG_INIT);
            }
        }
        __syncthreads();
    }

    // Reduce max across the 16 column-lanes (same quad = same rows)
    #pragma unroll
    for (int m = 1; m < 16; m <<= 1)
        #pragma unroll
        for (int s = 0; s < 4; ++s)
            #pragma unroll
            for (int r = 0; r < 4; ++r)
                vmax[s][r] = fmaxf(vmax[s][r], __shfl_xor(vmax[s][r], m, 64));

    if (l15 == 0) {
        #pragma unroll
        for (int s = 0; s < 4; ++s)
            #pragma unroll
            for (int r = 0; r < 4; ++r) {
                int row = rowBase + s * 16 + quad * 4 + r;
                partials[(size_t)part * NB * 16 + (size_t)row * 16 + (chunk & 15)] = vmax[s][r];
            }
    }
}

// Kernel 3: combine per-part chunk partials -> neg distances -> hinge -> mean.
__global__ void finalize_kernel(const float* __restrict__ partials,
                                const float* __restrict__ posArr,
                                float* __restrict__ out) {
    int row = blockIdx.x * 256 + threadIdx.x;    // grid = 16 -> 4096 rows
    const float* pa = partials + (size_t)row * 16;
    const float* pb = pa + (size_t)NB * 16;
    const float* pc = pb + (size_t)NB * 16;
    float ma = NEG_INIT, m0 = NEG_INIT, m1 = NEG_INIT;
    #pragma unroll
    for (int j = 0; j < 16; ++j) {
        ma = fmaxf(ma, pa[j]);
        m0 = fmaxf(m0, pb[j]);
        m1 = fmaxf(m1, pc[j]);
    }
    float n0 = sqrtf(fmaxf(2.0f - 2.0f * fmaxf(ma, m0), 1e-12f));
    float n1 = sqrtf(fmaxf(2.0f - 2.0f * fmaxf(ma, m1), 1e-12f));
    float l = fmaxf(posArr[row * 2 + 0] - n0 + 1.0f, 0.0f)
            + fmaxf(posArr[row * 2 + 1] - n1 + 1.0f, 0.0f);
    int lane = threadIdx.x & 63, wid = threadIdx.x >> 6;
    #pragma unroll
    for (int m = 1; m < 64; m <<= 1) l += __shfl_xor(l, m, 64);
    __shared__ float wsum[4];
    if (lane == 0) wsum[wid] = l;
    __syncthreads();
    if (threadIdx.x == 0) {
        float s = wsum[0] + wsum[1] + wsum[2] + wsum[3];
        atomicAdd(out, s * (1.0f / (NB * NP)));
    }
}

extern "C" void kernel_launch(void* const* d_in, const int* in_sizes, int n_in,
                              void* d_out, int out_size, void* d_ws, size_t ws_size,
                              hipStream_t stream) {
    const float* anchor   = (const float*)d_in[0];
    const float* positive = (const float*)d_in[1];
    const int*   labels   = (const int*)d_in[2];
    float* out = (float*)d_out;

    unsigned char* F = (unsigned char*)((char*)d_ws + WS_F_OFF);
    float* posArr    = (float*)((char*)d_ws + WS_POS_OFF);
    float* partials  = (float*)((char*)d_ws + WS_PART_OFF);

    norm_pos_kernel<<<TOT / 4, 256, 0, stream>>>(anchor, positive, F, posArr);
    gram_max_kernel<<<(NB / 256) * NCHUNK, 256, 0, stream>>>(F, labels, partials);
    hipMemsetAsync(d_out, 0, sizeof(float), stream);
    finalize_kernel<<<NB / 256, 256, 0, stream>>>(partials, posArr, out);
}

// Round 9
// 95.305 us; speedup vs baseline: 1.1044x; 1.0546x over previous
//
#include <hip/hip_runtime.h>
#include <hip/hip_bf16.h>

// Problem constants
#define NB    4096          // batch
#define ND    256           // dim
#define NP    2             // positives per anchor
#define TOT   (NB * 3)      // 12288 rows: [a | p0 | p1]
#define RB    256           // row bytes in F (fp8: 1 B/elem)
#define NCHUNK 48           // 3 parts x 16 chunks; each chunk within one part
#define COLS_PER_CHUNK 256
#define TILES (COLS_PER_CHUNK / 16)            // 16
#define NEG_INIT (-4.0f)

typedef float f32x4 __attribute__((ext_vector_type(4)));
typedef long  longx2 __attribute__((ext_vector_type(2)));

// ws layout (bytes)
#define WS_F_OFF    0                            // uchar[12288*256] fp8 normalized
#define WS_POS_OFF  (TOT * RB)                   // float[4096*2] pos distances
#define WS_PART_OFF (WS_POS_OFF + NB * NP * 4)   // float[3][4096][16] partial maxima

// Kernel 1: normalize rows of [a | p0 | p1] -> fp8 e4m3 matrix F; p-rows also
// emit the exact fp32 positive distance. One wave per row.
__global__ void norm_pos_kernel(const float* __restrict__ anchor,
                                const float* __restrict__ positive,
                                unsigned char* __restrict__ F,
                                float* __restrict__ posArr) {
    int wid = threadIdx.x >> 6, lane = threadIdx.x & 63;
    int row = blockIdx.x * 4 + wid;              // grid = 3072
    if (row < NB) {
        const float* src = anchor + (size_t)row * ND;
        float4 x = *(const float4*)(src + lane * 4);
        float ss = x.x * x.x + x.y * x.y + x.z * x.z + x.w * x.w;
        #pragma unroll
        for (int m = 1; m < 64; m <<= 1) ss += __shfl_xor(ss, m, 64);
        float inv = 1.0f / fmaxf(sqrtf(ss), 1e-12f);
        int pk = __builtin_amdgcn_cvt_pk_fp8_f32(x.x * inv, x.y * inv, 0, false);
        pk = __builtin_amdgcn_cvt_pk_fp8_f32(x.z * inv, x.w * inv, pk, true);
        *(int*)(F + (size_t)row * RB + lane * 4) = pk;
    } else {
        int q = row - NB;
        int v = q >> 12;                         // 0 or 1
        int j = q & (NB - 1);
        const float* sp = positive + (size_t)(j * NP + v) * ND;
        const float* sa = anchor + (size_t)j * ND;
        float4 xp = *(const float4*)(sp + lane * 4);
        float4 xa = *(const float4*)(sa + lane * 4);
        float sspv = xp.x * xp.x + xp.y * xp.y + xp.z * xp.z + xp.w * xp.w;
        float ssa  = xa.x * xa.x + xa.y * xa.y + xa.z * xa.z + xa.w * xa.w;
        float dot  = xa.x * xp.x + xa.y * xp.y + xa.z * xp.z + xa.w * xp.w;
        #pragma unroll
        for (int m = 1; m < 64; m <<= 1) {
            sspv += __shfl_xor(sspv, m, 64);
            ssa  += __shfl_xor(ssa, m, 64);
            dot  += __shfl_xor(dot, m, 64);
        }
        float invp = 1.0f / fmaxf(sqrtf(sspv), 1e-12f);
        int pk = __builtin_amdgcn_cvt_pk_fp8_f32(xp.x * invp, xp.y * invp, 0, false);
        pk = __builtin_amdgcn_cvt_pk_fp8_f32(xp.z * invp, xp.w * invp, pk, true);
        *(int*)(F + (size_t)row * RB + lane * 4) = pk;
        if (lane == 0) {
            float inva = 1.0f / fmaxf(sqrtf(ssa), 1e-12f);
            float dn = dot * inva * invp;
            float sq = 2.0f - 2.0f * dn;
            posArr[j * NP + v] = sqrtf(fmaxf(sq, 1e-12f));
        }
    }
}

// Kernel 2: fused masked-max Gram, FP8, BARRIER-FREE K-loop.
// The whole 256-col B chunk (64 KB fp8) is staged to LDS once, in a
// tile-sliced lane-contiguous layout: byte (tile, kk, quad, l15, b) at
//   tile*4096 + kk*512 + (quad*16 + l15)*8 + b
// so each ds_read_b64 in the loop is one contiguous 512 B wave access
// (floor LDS rate, no conflicts). The K-loop then has NO __syncthreads and
// NO global loads -> no vmcnt(0) barrier drain (the m97-structure leak that
// R1-R8 profiling isolated). 2 blocks/CU (65 KB LDS each).
__global__ __launch_bounds__(256, 2) void gram_max_kernel(
        const unsigned char* __restrict__ F,
        const int* __restrict__ labels,
        float* __restrict__ partials) {
    __shared__ unsigned char ldsB[TILES * 4096];  // 64 KB
    __shared__ int slab[COLS_PER_CHUNK];          // 1 KB column labels
    int tid = threadIdx.x;
    int wid = tid >> 6, lane = tid & 63;
    int l15 = lane & 15, quad = lane >> 4;

    int id = blockIdx.x;                         // 0..767
    int chunk = id >> 4;                         // 0..47
    int rbi   = id & 15;                         // 0..15 row-block index

    int rowBase = rbi * 256 + wid * 64;
    int col0 = chunk * COLS_PER_CHUNK;
    int part = chunk >> 4;                       // 0=aa, 1=p0, 2=p1
    const unsigned char* Fb = F;

    // ---- A preload: af[s][kk] = 8 fp8 K-bytes, row rowBase+s*16+l15,
    //      K-offset quad*8 + kk*32 (verified fp8 16x16x32 A layout, R8).
    long af[4][8];
    #pragma unroll
    for (int s = 0; s < 4; ++s) {
        const unsigned char* ar = Fb + (size_t)(rowBase + s * 16 + l15) * RB + quad * 8;
        #pragma unroll
        for (int kk = 0; kk < 8; ++kk)
            af[s][kk] = *(const long*)(ar + kk * 32);
    }
    // Row labels, byte-packed (labels < 200 fit a byte).
    unsigned rlp[4];
    #pragma unroll
    for (int s = 0; s < 4; ++s) {
        const int* lb = labels + rowBase + s * 16 + quad * 4;
        rlp[s] = (unsigned)lb[0] | ((unsigned)lb[1] << 8)
               | ((unsigned)lb[2] << 16) | ((unsigned)lb[3] << 24);
    }

    // ---- Stage the whole B chunk: thread tid owns column cc = tid.
    slab[tid] = labels[(col0 & (NB - 1)) + tid];
    {
        const unsigned char* g = Fb + (size_t)(col0 + tid) * RB;
        int tilec = tid >> 4, c15 = tid & 15;
        unsigned char* dbase = ldsB + tilec * 4096 + c15 * 8;
        #pragma unroll
        for (int kk = 0; kk < 8; ++kk) {
            longx2 u = *(const longx2*)(g + kk * 32);
            longx2 v = *(const longx2*)(g + kk * 32 + 16);
            unsigned char* d = dbase + kk * 512;
            *(long*)(d + 0 * 128) = u.x;
            *(long*)(d + 1 * 128) = u.y;
            *(long*)(d + 2 * 128) = v.x;
            *(long*)(d + 3 * 128) = v.y;
        }
    }
    __syncthreads();   // the ONLY barrier

    float vmax[4][4];
    #pragma unroll
    for (int s = 0; s < 4; ++s)
        #pragma unroll
        for (int r = 0; r < 4; ++r) vmax[s][r] = NEG_INIT;

    // ---- Barrier-free K-loop: pure ds_read + MFMA + mask-fold.
    #pragma unroll 2
    for (int ct = 0; ct < TILES; ++ct) {
        long bfr[8];
        #pragma unroll
        for (int kk = 0; kk < 8; ++kk)
            bfr[kk] = *(const long*)&ldsB[ct * 4096 + kk * 512 + lane * 8];

        int lc = slab[ct * 16 + l15];
        unsigned lcq = (unsigned)lc * 0x01010101u;

        f32x4 acc[4];
        #pragma unroll
        for (int s = 0; s < 4; ++s) acc[s] = (f32x4){0.f, 0.f, 0.f, 0.f};
        #pragma unroll
        for (int kk = 0; kk < 8; ++kk)
            #pragma unroll
            for (int s = 0; s < 4; ++s)
                acc[s] = __builtin_amdgcn_mfma_f32_16x16x32_fp8_fp8(af[s][kk], bfr[kk], acc[s], 0, 0, 0);

        #pragma unroll
        for (int s = 0; s < 4; ++s) {
            unsigned x = rlp[s] ^ lcq;         // byte r == 0 iff labels equal
            #pragma unroll
            for (int r = 0; r < 4; ++r) {
                bool neq = ((x >> (8 * r)) & 0xffu) != 0u;
                vmax[s][r] = fmaxf(vmax[s][r], neq ? acc[s][r] : NEG_INIT);
            }
        }
    }

    // Reduce max across the 16 column-lanes (same quad = same rows)
    #pragma unroll
    for (int m = 1; m < 16; m <<= 1)
        #pragma unroll
        for (int s = 0; s < 4; ++s)
            #pragma unroll
            for (int r = 0; r < 4; ++r)
                vmax[s][r] = fmaxf(vmax[s][r], __shfl_xor(vmax[s][r], m, 64));

    if (l15 == 0) {
        #pragma unroll
        for (int s = 0; s < 4; ++s)
            #pragma unroll
            for (int r = 0; r < 4; ++r) {
                int row = rowBase + s * 16 + quad * 4 + r;
                partials[(size_t)part * NB * 16 + (size_t)row * 16 + (chunk & 15)] = vmax[s][r];
            }
    }
}

// Kernel 3: combine per-part chunk partials -> neg distances -> hinge -> mean.
__global__ void finalize_kernel(const float* __restrict__ partials,
                                const float* __restrict__ posArr,
                                float* __restrict__ out) {
    int row = blockIdx.x * 256 + threadIdx.x;    // grid = 16 -> 4096 rows
    const float* pa = partials + (size_t)row * 16;
    const float* pb = pa + (size_t)NB * 16;
    const float* pc = pb + (size_t)NB * 16;
    float ma = NEG_INIT, m0 = NEG_INIT, m1 = NEG_INIT;
    #pragma unroll
    for (int j = 0; j < 16; ++j) {
        ma = fmaxf(ma, pa[j]);
        m0 = fmaxf(m0, pb[j]);
        m1 = fmaxf(m1, pc[j]);
    }
    float n0 = sqrtf(fmaxf(2.0f - 2.0f * fmaxf(ma, m0), 1e-12f));
    float n1 = sqrtf(fmaxf(2.0f - 2.0f * fmaxf(ma, m1), 1e-12f));
    float l = fmaxf(posArr[row * 2 + 0] - n0 + 1.0f, 0.0f)
            + fmaxf(posArr[row * 2 + 1] - n1 + 1.0f, 0.0f);
    int lane = threadIdx.x & 63, wid = threadIdx.x >> 6;
    #pragma unroll
    for (int m = 1; m < 64; m <<= 1) l += __shfl_xor(l, m, 64);
    __shared__ float wsum[4];
    if (lane == 0) wsum[wid] = l;
    __syncthreads();
    if (threadIdx.x == 0) {
        float s = wsum[0] + wsum[1] + wsum[2] + wsum[3];
        atomicAdd(out, s * (1.0f / (NB * NP)));
    }
}

extern "C" void kernel_launch(void* const* d_in, const int* in_sizes, int n_in,
                              void* d_out, int out_size, void* d_ws, size_t ws_size,
                              hipStream_t stream) {
    const float* anchor   = (const float*)d_in[0];
    const float* positive = (const float*)d_in[1];
    const int*   labels   = (const int*)d_in[2];
    float* out = (float*)d_out;

    unsigned char* F = (unsigned char*)((char*)d_ws + WS_F_OFF);
    float* posArr    = (float*)((char*)d_ws + WS_POS_OFF);
    float* partials  = (float*)((char*)d_ws + WS_PART_OFF);

    norm_pos_kernel<<<TOT / 4, 256, 0, stream>>>(anchor, positive, F, posArr);
    gram_max_kernel<<<(NB / 256) * NCHUNK, 256, 0, stream>>>(F, labels, partials);
    hipMemsetAsync(d_out, 0, sizeof(float), stream);
    finalize_kernel<<<NB / 256, 256, 0, stream>>>(partials, posArr, out);
}